// Round 21
// baseline (65.380 us; speedup 1.0000x reference)
//
#include <hip/hip_runtime.h>
#include <stdint.h>

#define IC 128
#define OC 256
#define RR 64
#define CCOLS 64
#define HO 62
#define WO 62
#define NB 16

// Fragment-major dense bf16 weights: W9Tf[chunk][g][lane][16B],
// chunk = kp*8+ck (72), g = oc>>5 (8), lane = (oc&31)+32*khalf.
#define W9T_BYTES (9 * OC * IC * 2)   // 589824
#define CHUNK_STRIDE 8192
// B LDS layout: [krow 3][octet 16][x 64][16B] = 48 KB + 64 B pad (max read
// byte = 49184; pad keeps unclamped x1<=65 reads in-bounds). 3 x 49216 =
// 147648 <= 160 KB -> 3 blocks/CU.
#define LDS_TOTAL 49216

typedef __bf16 bf16x8 __attribute__((ext_vector_type(8)));
typedef float f32x16 __attribute__((ext_vector_type(16)));

__device__ __forceinline__ unsigned short f2bf(float f) {
    unsigned u = __builtin_bit_cast(unsigned, f);
    u += 0x7FFFu + ((u >> 16) & 1u);   // round-to-nearest-even
    return (unsigned short)(u >> 16);
}

// prep: blocks 0..OC-1 scatter weights; block OC densifies the bias.
__global__ void prep_weights(const float* __restrict__ wv,
                             const int* __restrict__ iwi,
                             const int* __restrict__ flen,
                             const int* __restrict__ sp,
                             unsigned char* __restrict__ W9Tf,
                             const int* __restrict__ bias_index,
                             const float* __restrict__ bias_value,
                             float* __restrict__ bias_dense, int nbias) {
    if (blockIdx.x == OC) {
        int t = threadIdx.x;
        if (t < OC) bias_dense[t] = 0.f;
        __syncthreads();
        if (t < nbias) atomicAdd(&bias_dense[bias_index[t]], bias_value[t]);
        return;
    }
    const int oc = blockIdx.x;
    const int s = sp[oc];
    const int n = flen[oc];
    const int g = oc >> 5;
    for (int t = threadIdx.x; t < n; t += blockDim.x) {
        const int ix = iwi[s + t];          // c*4096 + ky*64 + kx
        const int c = ix >> 12;
        const int rem = ix & 4095;
        const int ky = rem >> 6, kx = rem & 63;
        const int kp = ky * 3 + kx;
        const int ck = c >> 4;
        const int khalf = (c >> 3) & 1;
        const int lane = (oc & 31) + (khalf << 5);
        const size_t off = (size_t)(kp * 8 + ck) * CHUNK_STRIDE +
                           g * 1024 + lane * 16 + (c & 7) * 2;
        *(unsigned short*)(W9Tf + off) = f2bf(wv[s + t]);
    }
}

// One K-chunk step, 4 accumulator chains. AV0/AV1 = the two A-stream
// fragments loaded 4 steps ago (opaque asm). b0c/b1c = B fragments read
// 1 step ago (opaque asm). Steady state: vmcnt(6) [8 A-loads in flight,
// consume oldest pair], lgkmcnt(2) [4 B-reads in flight, consume oldest
// pair]. sched_barrier(0) after the waitcnt (rule #18).
#define KSTEP1(IDX, AV0, AV1, VN, LGN)                                        \
  {                                                                           \
    if constexpr ((IDX) + 1 < 72) {                                           \
      constexpr int i1_ = (IDX) + 1;                                          \
      constexpr int kp1_ = i1_ >> 3, ck1_ = i1_ & 7;                          \
      constexpr int o1_ = (kp1_ / 3) * 16384 + ck1_ * 2048 + (kp1_ % 3) * 16; \
      asm volatile("ds_read_b128 %0, %1" : "=v"(b0n) : "v"(bB + o1_));        \
      asm volatile("ds_read_b128 %0, %1" : "=v"(b1n) : "v"(bB + o1_ + 512));  \
    }                                                                         \
    asm volatile("s_waitcnt vmcnt(" VN ") lgkmcnt(" LGN ")"                   \
                 : "+v"(AV0), "+v"(AV1));                                     \
    __builtin_amdgcn_sched_barrier(0);                                        \
    c00 = __builtin_amdgcn_mfma_f32_32x32x16_bf16(AV0, b0c, c00, 0, 0, 0);    \
    c10 = __builtin_amdgcn_mfma_f32_32x32x16_bf16(AV1, b0c, c10, 0, 0, 0);    \
    c01 = __builtin_amdgcn_mfma_f32_32x32x16_bf16(AV0, b1c, c01, 0, 0, 0);    \
    c11 = __builtin_amdgcn_mfma_f32_32x32x16_bf16(AV1, b1c, c11, 0, 0, 0);    \
    if constexpr ((IDX) + 4 < 72) {                                           \
      asm volatile("global_load_dwordx4 %0, %1, off"                          \
                   : "=v"(AV0)                                                \
                   : "v"(pA0 + (size_t)((IDX) + 4) * CHUNK_STRIDE));          \
      asm volatile("global_load_dwordx4 %0, %1, off"                          \
                   : "=v"(AV1)                                                \
                   : "v"(pA1 + (size_t)((IDX) + 4) * CHUNK_STRIDE));          \
    }                                                                         \
    if constexpr ((IDX) + 1 < 72) { b0c = b0n; b1c = b1n; }                   \
  }

#define K4(I) KSTEP1((I)+0, a0S0, a1S0, "6", "2") \
              KSTEP1((I)+1, a0S1, a1S1, "6", "2") \
              KSTEP1((I)+2, a0S2, a1S2, "6", "2") \
              KSTEP1((I)+3, a0S3, a1S3, "6", "2")

// Block = one output row (b, y) x all 256 oc. 256 threads = 4 waves.
// Wave w: oc-groups {2w, 2w+1} x 64 x (2 n-tiles) = 4 accumulator chains,
// 4 MFMAs/step (129 cyc pipe/wave/step; R20's 2 chains starved the pipe
// at 25% with a 15us/CU MFMA floor). 3 blocks/CU via 49216 B LDS +
// launch_bounds(256,3); dual opaque A-streams 4-deep + opaque B 1-deep.
__global__ __launch_bounds__(256, 3) void conv_mfma(
    const float* __restrict__ images,
    const unsigned char* __restrict__ W9Tf,
    const float* __restrict__ bias_dense,
    float* __restrict__ out)
{
    const int y = blockIdx.x;
    const int b = blockIdx.y;
    const int t = threadIdx.x;
    const int w = t >> 6;             // 0..3
    const int l = t & 63;
    const int lm = l & 31;            // m-row / n-col within frag
    const int lhi = l >> 5;           // k-half

    __shared__ unsigned char lds[LDS_TOTAL];

    const float* __restrict__ imgb = images + (size_t)b * (IC * RR * CCOLS);

    // ---- stage B: 3 rows -> [krow][octet][x][16B] (conflict-free) ----
    {
        const int xs = t & 63;
        const int og = t >> 6;              // 0..3, wave-uniform
        #pragma unroll
        for (int krow = 0; krow < 3; ++krow) {
            #pragma unroll
            for (int h = 0; h < 4; ++h) {
                const int o = og + 4 * h;           // octet 0..15
                const int c0 = o * 8;
                const float* __restrict__ p =
                    imgb + (size_t)c0 * (RR * CCOLS) + (y + krow) * CCOLS + xs;
                unsigned v0, v1, v2, v3;
                v0 = (unsigned)f2bf(p[0])              | ((unsigned)f2bf(p[RR * CCOLS])     << 16);
                v1 = (unsigned)f2bf(p[2 * RR * CCOLS]) | ((unsigned)f2bf(p[3 * RR * CCOLS]) << 16);
                v2 = (unsigned)f2bf(p[4 * RR * CCOLS]) | ((unsigned)f2bf(p[5 * RR * CCOLS]) << 16);
                v3 = (unsigned)f2bf(p[6 * RR * CCOLS]) | ((unsigned)f2bf(p[7 * RR * CCOLS]) << 16);
                // wave writes 64 consecutive 16B slots = 1 KB contiguous
                *(uint4*)(lds + krow * 16384 + o * 1024 + xs * 16) =
                    make_uint4(v0, v1, v2, v3);
            }
        }
    }

    // lane's coalesced A bases (global) and B base (LDS byte address)
    const unsigned char* __restrict__ pA0 = W9Tf + (2 * w + 0) * 1024 + l * 16;
    const unsigned char* __restrict__ pA1 = W9Tf + (2 * w + 1) * 1024 + l * 16;
    const unsigned bB = (unsigned)(uintptr_t)(lds + lhi * 1024 + lm * 16);

    __syncthreads();   // B staged; all counters drained

    // prologue: A chunks 0..3 (both streams, issue order = count order)
    // and B chunk 0 in flight (all opaque)
    bf16x8 a0S0, a0S1, a0S2, a0S3, a1S0, a1S1, a1S2, a1S3;
    bf16x8 b0c, b1c, b0n, b1n;
    asm volatile("global_load_dwordx4 %0, %1, off" : "=v"(a0S0) : "v"(pA0));
    asm volatile("global_load_dwordx4 %0, %1, off" : "=v"(a1S0) : "v"(pA1));
    asm volatile("global_load_dwordx4 %0, %1, off" : "=v"(a0S1) : "v"(pA0 + CHUNK_STRIDE));
    asm volatile("global_load_dwordx4 %0, %1, off" : "=v"(a1S1) : "v"(pA1 + CHUNK_STRIDE));
    asm volatile("global_load_dwordx4 %0, %1, off" : "=v"(a0S2) : "v"(pA0 + 2 * CHUNK_STRIDE));
    asm volatile("global_load_dwordx4 %0, %1, off" : "=v"(a1S2) : "v"(pA1 + 2 * CHUNK_STRIDE));
    asm volatile("global_load_dwordx4 %0, %1, off" : "=v"(a0S3) : "v"(pA0 + 3 * CHUNK_STRIDE));
    asm volatile("global_load_dwordx4 %0, %1, off" : "=v"(a1S3) : "v"(pA1 + 3 * CHUNK_STRIDE));
    asm volatile("ds_read_b128 %0, %1" : "=v"(b0c) : "v"(bB));
    asm volatile("ds_read_b128 %0, %1" : "=v"(b1c) : "v"(bB + 512u));

    // named accumulators c<m><n> (static indexing -> no scratch)
    f32x16 c00 = {}, c01 = {}, c10 = {}, c11 = {};

    // 72 straight-line K-steps; steady vmcnt(6)/lgkmcnt(2); counted tail
    K4(0) K4(4) K4(8) K4(12) K4(16) K4(20) K4(24) K4(28) K4(32)
    K4(36) K4(40) K4(44) K4(48) K4(52) K4(56) K4(60) K4(64)
    KSTEP1(68, a0S0, a1S0, "6", "2") KSTEP1(69, a0S1, a1S1, "4", "2")
    KSTEP1(70, a0S2, a1S2, "2", "2") KSTEP1(71, a0S3, a1S3, "0", "0")

    // ---- epilogue: bias + store ----
    // C/D 32x32: col = lane&31, row = (reg&3) + 8*(reg>>2) + 4*(lane>>5)
    #pragma unroll
    for (int m = 0; m < 2; ++m) {
        const int ocw = (2 * w + m) * 32;
        const f32x16 d0 = m ? c10 : c00;
        const f32x16 d1 = m ? c11 : c01;
        #pragma unroll
        for (int r = 0; r < 16; ++r) {
            const int oc = ocw + (r & 3) + 8 * (r >> 2) + 4 * lhi;
            const float bv = bias_dense[oc];
            const size_t ob = (((size_t)b * OC + oc) * HO + y) * WO;
            out[ob + lm] = d0[r] + bv;               // x = lm < 62 always
            if (lm < 30)
                out[ob + 32 + lm] = d1[r] + bv;      // x = 32+lm, clip at 62
        }
    }
}

extern "C" void kernel_launch(void* const* d_in, const int* in_sizes, int n_in,
                              void* d_out, int out_size, void* d_ws, size_t ws_size,
                              hipStream_t stream) {
    const float* images             = (const float*)d_in[0];
    const float* weight_value       = (const float*)d_in[1];
    const int*   image_weight_index = (const int*)d_in[2];
    const int*   filter_lengths     = (const int*)d_in[3];
    const int*   start_points       = (const int*)d_in[4];
    const int*   bias_index         = (const int*)d_in[5];
    const float* bias_value         = (const float*)d_in[6];
    float* out = (float*)d_out;

    unsigned char* W9Tf = (unsigned char*)d_ws;
    float* bias_dense = (float*)((char*)d_ws + W9T_BYTES);

    hipMemsetAsync(d_ws, 0, W9T_BYTES, stream);
    prep_weights<<<OC + 1, 256, 0, stream>>>(weight_value, image_weight_index,
                                             filter_lengths, start_points, W9Tf,
                                             bias_index, bias_value, bias_dense,
                                             in_sizes[5]);

    dim3 grid(HO, NB);
    conv_mfma<<<grid, 256, 0, stream>>>(images, W9Tf, bias_dense, out);
}

// Round 22
// 60.056 us; speedup vs baseline: 1.0886x; 1.0886x over previous
//
#include <hip/hip_runtime.h>
#include <stdint.h>

#define IC 128
#define OC 256
#define RR 64
#define CCOLS 64
#define HO 62
#define WO 62
#define NB 16

// Fragment-major dense bf16 weights: W9Tf[chunk][g][lane][16B],
// chunk = kp*8+ck (72), g = oc>>5 (8), lane = (oc&31)+32*khalf.
#define W9T_BYTES (9 * OC * IC * 2)   // 589824
#define CHUNK_STRIDE 8192
// B LDS layout: [krow 4][octet 16][x 64][16B] = 64 KB + 64 B pad (max read
// byte 65552; unclamped x<=65 reads land in pad, outputs never stored).
// 2 x 65600 <= 160 KB -> 2 blocks/CU.
#define LDS_TOTAL 65600

typedef __bf16 bf16x8 __attribute__((ext_vector_type(8)));
typedef float f32x16 __attribute__((ext_vector_type(16)));

__device__ __forceinline__ unsigned short f2bf(float f) {
    unsigned u = __builtin_bit_cast(unsigned, f);
    u += 0x7FFFu + ((u >> 16) & 1u);   // round-to-nearest-even
    return (unsigned short)(u >> 16);
}

// prep: blocks 0..OC-1 scatter weights; block OC densifies the bias.
__global__ void prep_weights(const float* __restrict__ wv,
                             const int* __restrict__ iwi,
                             const int* __restrict__ flen,
                             const int* __restrict__ sp,
                             unsigned char* __restrict__ W9Tf,
                             const int* __restrict__ bias_index,
                             const float* __restrict__ bias_value,
                             float* __restrict__ bias_dense, int nbias) {
    if (blockIdx.x == OC) {
        int t = threadIdx.x;
        if (t < OC) bias_dense[t] = 0.f;
        __syncthreads();
        if (t < nbias) atomicAdd(&bias_dense[bias_index[t]], bias_value[t]);
        return;
    }
    const int oc = blockIdx.x;
    const int s = sp[oc];
    const int n = flen[oc];
    const int g = oc >> 5;
    for (int t = threadIdx.x; t < n; t += blockDim.x) {
        const int ix = iwi[s + t];          // c*4096 + ky*64 + kx
        const int c = ix >> 12;
        const int rem = ix & 4095;
        const int ky = rem >> 6, kx = rem & 63;
        const int kp = ky * 3 + kx;
        const int ck = c >> 4;
        const int khalf = (c >> 3) & 1;
        const int lane = (oc & 31) + (khalf << 5);
        const size_t off = (size_t)(kp * 8 + ck) * CHUNK_STRIDE +
                           g * 1024 + lane * 16 + (c & 7) * 2;
        *(unsigned short*)(W9Tf + off) = f2bf(wv[s + t]);
    }
}

// One K-chunk step, 8 accumulator chains (2 oc x 2 y x 2 n). AV0/AV1 =
// A-stream fragments loaded 4 steps ago (opaque). b<yy><n>c = B fragments
// read 1 step ago (opaque). Steady: vmcnt(6) [8 A-loads in flight, consume
// oldest pair], lgkmcnt(4) [8 B-reads in flight, consume oldest 4].
// sched_barrier(0) after the waitcnt (rule #18); setprio around the MFMA
// cluster (T5: waves are role-staggered by the counted waits here).
#define KSTEP1(IDX, AV0, AV1, VN, LGN)                                        \
  {                                                                           \
    if constexpr ((IDX) + 1 < 72) {                                           \
      constexpr int i1_ = (IDX) + 1;                                          \
      constexpr int kp1_ = i1_ >> 3, ck1_ = i1_ & 7;                          \
      constexpr int ky1_ = kp1_ / 3;                                          \
      constexpr int o1_ = ky1_ * 16384 + ck1_ * 2048 + (kp1_ % 3) * 16;       \
      asm volatile("ds_read_b128 %0, %1" : "=v"(b00n) : "v"(bB + o1_));       \
      asm volatile("ds_read_b128 %0, %1" : "=v"(b01n) : "v"(bB + o1_ + 512)); \
      asm volatile("ds_read_b128 %0, %1" : "=v"(b10n) : "v"(bB + o1_ + 16384)); \
      asm volatile("ds_read_b128 %0, %1" : "=v"(b11n) : "v"(bB + o1_ + 16384 + 512)); \
    }                                                                         \
    asm volatile("s_waitcnt vmcnt(" VN ") lgkmcnt(" LGN ")"                   \
                 : "+v"(AV0), "+v"(AV1));                                     \
    __builtin_amdgcn_sched_barrier(0);                                        \
    __builtin_amdgcn_s_setprio(1);                                            \
    c000 = __builtin_amdgcn_mfma_f32_32x32x16_bf16(AV0, b00c, c000, 0, 0, 0); \
    c100 = __builtin_amdgcn_mfma_f32_32x32x16_bf16(AV1, b00c, c100, 0, 0, 0); \
    c001 = __builtin_amdgcn_mfma_f32_32x32x16_bf16(AV0, b01c, c001, 0, 0, 0); \
    c101 = __builtin_amdgcn_mfma_f32_32x32x16_bf16(AV1, b01c, c101, 0, 0, 0); \
    c010 = __builtin_amdgcn_mfma_f32_32x32x16_bf16(AV0, b10c, c010, 0, 0, 0); \
    c110 = __builtin_amdgcn_mfma_f32_32x32x16_bf16(AV1, b10c, c110, 0, 0, 0); \
    c011 = __builtin_amdgcn_mfma_f32_32x32x16_bf16(AV0, b11c, c011, 0, 0, 0); \
    c111 = __builtin_amdgcn_mfma_f32_32x32x16_bf16(AV1, b11c, c111, 0, 0, 0); \
    __builtin_amdgcn_s_setprio(0);                                            \
    if constexpr ((IDX) + 4 < 72) {                                           \
      asm volatile("global_load_dwordx4 %0, %1, off"                          \
                   : "=v"(AV0)                                                \
                   : "v"(pA0 + (size_t)((IDX) + 4) * CHUNK_STRIDE));          \
      asm volatile("global_load_dwordx4 %0, %1, off"                          \
                   : "=v"(AV1)                                                \
                   : "v"(pA1 + (size_t)((IDX) + 4) * CHUNK_STRIDE));          \
    }                                                                         \
    if constexpr ((IDX) + 1 < 72) {                                           \
      b00c = b00n; b01c = b01n; b10c = b10n; b11c = b11n;                     \
    }                                                                         \
  }

#define K4(I) KSTEP1((I)+0, a0S0, a1S0, "6", "4") \
              KSTEP1((I)+1, a0S1, a1S1, "6", "4") \
              KSTEP1((I)+2, a0S2, a1S2, "6", "4") \
              KSTEP1((I)+3, a0S3, a1S3, "6", "4")

// Block = (b, 2 output rows) x all 256 oc. 256 threads = 4 waves.
// Wave w: oc-groups {2w,2w+1} x 2 n-tiles x 2 y-rows = 8 chains, 8 MFMAs
// per step (258 cyc pipe/wave/step — 2x R21; A reused across y halves the
// TA-stream). R12 geometry + the R19/R20 opaque pipelines it never had.
__global__ __launch_bounds__(256, 1) void conv_mfma(
    const float* __restrict__ images,
    const unsigned char* __restrict__ W9Tf,
    const float* __restrict__ bias_dense,
    float* __restrict__ out)
{
    const int y0 = blockIdx.x * 2;
    const int b = blockIdx.y;
    const int t = threadIdx.x;
    const int w = t >> 6;             // 0..3
    const int l = t & 63;
    const int lm = l & 31;            // m-row / n-col within frag
    const int lhi = l >> 5;           // k-half

    __shared__ unsigned char lds[LDS_TOTAL];

    const float* __restrict__ imgb = images + (size_t)b * (IC * RR * CCOLS);

    // ---- stage B: 4 rows -> [krow][octet][x][16B] (conflict-free) ----
    {
        const int xs = t & 63;
        const int og = t >> 6;              // 0..3, wave-uniform
        #pragma unroll
        for (int krow = 0; krow < 4; ++krow) {
            #pragma unroll
            for (int h = 0; h < 4; ++h) {
                const int o = og + 4 * h;           // octet 0..15
                const int c0 = o * 8;
                const float* __restrict__ p =
                    imgb + (size_t)c0 * (RR * CCOLS) + (y0 + krow) * CCOLS + xs;
                unsigned v0, v1, v2, v3;
                v0 = (unsigned)f2bf(p[0])              | ((unsigned)f2bf(p[RR * CCOLS])     << 16);
                v1 = (unsigned)f2bf(p[2 * RR * CCOLS]) | ((unsigned)f2bf(p[3 * RR * CCOLS]) << 16);
                v2 = (unsigned)f2bf(p[4 * RR * CCOLS]) | ((unsigned)f2bf(p[5 * RR * CCOLS]) << 16);
                v3 = (unsigned)f2bf(p[6 * RR * CCOLS]) | ((unsigned)f2bf(p[7 * RR * CCOLS]) << 16);
                *(uint4*)(lds + krow * 16384 + o * 1024 + xs * 16) =
                    make_uint4(v0, v1, v2, v3);
            }
        }
    }

    // lane's coalesced A bases (global) and B base (LDS byte address)
    const unsigned char* __restrict__ pA0 = W9Tf + (2 * w + 0) * 1024 + l * 16;
    const unsigned char* __restrict__ pA1 = W9Tf + (2 * w + 1) * 1024 + l * 16;
    const unsigned bB = (unsigned)(uintptr_t)(lds + lhi * 1024 + lm * 16);

    __syncthreads();   // B staged; all counters drained

    // prologue: A chunks 0..3 (both streams) and B step 0 in flight
    bf16x8 a0S0, a0S1, a0S2, a0S3, a1S0, a1S1, a1S2, a1S3;
    bf16x8 b00c, b01c, b10c, b11c, b00n, b01n, b10n, b11n;
    asm volatile("global_load_dwordx4 %0, %1, off" : "=v"(a0S0) : "v"(pA0));
    asm volatile("global_load_dwordx4 %0, %1, off" : "=v"(a1S0) : "v"(pA1));
    asm volatile("global_load_dwordx4 %0, %1, off" : "=v"(a0S1) : "v"(pA0 + CHUNK_STRIDE));
    asm volatile("global_load_dwordx4 %0, %1, off" : "=v"(a1S1) : "v"(pA1 + CHUNK_STRIDE));
    asm volatile("global_load_dwordx4 %0, %1, off" : "=v"(a0S2) : "v"(pA0 + 2 * CHUNK_STRIDE));
    asm volatile("global_load_dwordx4 %0, %1, off" : "=v"(a1S2) : "v"(pA1 + 2 * CHUNK_STRIDE));
    asm volatile("global_load_dwordx4 %0, %1, off" : "=v"(a0S3) : "v"(pA0 + 3 * CHUNK_STRIDE));
    asm volatile("global_load_dwordx4 %0, %1, off" : "=v"(a1S3) : "v"(pA1 + 3 * CHUNK_STRIDE));
    asm volatile("ds_read_b128 %0, %1" : "=v"(b00c) : "v"(bB));
    asm volatile("ds_read_b128 %0, %1" : "=v"(b01c) : "v"(bB + 512u));
    asm volatile("ds_read_b128 %0, %1" : "=v"(b10c) : "v"(bB + 16384u));
    asm volatile("ds_read_b128 %0, %1" : "=v"(b11c) : "v"(bB + 16384u + 512u));

    // named accumulators c<m><yy><n> (static indexing -> no scratch)
    f32x16 c000 = {}, c001 = {}, c010 = {}, c011 = {};
    f32x16 c100 = {}, c101 = {}, c110 = {}, c111 = {};

    // 72 straight-line K-steps; steady vmcnt(6)/lgkmcnt(4); counted tail
    K4(0) K4(4) K4(8) K4(12) K4(16) K4(20) K4(24) K4(28) K4(32)
    K4(36) K4(40) K4(44) K4(48) K4(52) K4(56) K4(60) K4(64)
    KSTEP1(68, a0S0, a1S0, "6", "4") KSTEP1(69, a0S1, a1S1, "4", "4")
    KSTEP1(70, a0S2, a1S2, "2", "4") KSTEP1(71, a0S3, a1S3, "0", "0")

    // ---- epilogue: bias + store ----
    // C/D 32x32: col = lane&31, row = (reg&3) + 8*(reg>>2) + 4*(lane>>5)
    #pragma unroll
    for (int m = 0; m < 2; ++m) {
        const int ocw = (2 * w + m) * 32;
        const f32x16 d00 = m ? c100 : c000;   // [y0][n0]
        const f32x16 d01 = m ? c101 : c001;   // [y0][n1]
        const f32x16 d10 = m ? c110 : c010;   // [y1][n0]
        const f32x16 d11 = m ? c111 : c011;   // [y1][n1]
        #pragma unroll
        for (int r = 0; r < 16; ++r) {
            const int oc = ocw + (r & 3) + 8 * (r >> 2) + 4 * lhi;
            const float bv = bias_dense[oc];
            const size_t ob0 = (((size_t)b * OC + oc) * HO + y0) * WO;
            out[ob0 + lm] = d00[r] + bv;             // x = lm < 62 always
            if (lm < 30)
                out[ob0 + 32 + lm] = d01[r] + bv;    // x = 32+lm, clip at 62
            const size_t ob1 = ob0 + WO;             // row y0+1
            out[ob1 + lm] = d10[r] + bv;
            if (lm < 30)
                out[ob1 + 32 + lm] = d11[r] + bv;
        }
    }
}

extern "C" void kernel_launch(void* const* d_in, const int* in_sizes, int n_in,
                              void* d_out, int out_size, void* d_ws, size_t ws_size,
                              hipStream_t stream) {
    const float* images             = (const float*)d_in[0];
    const float* weight_value       = (const float*)d_in[1];
    const int*   image_weight_index = (const int*)d_in[2];
    const int*   filter_lengths     = (const int*)d_in[3];
    const int*   start_points       = (const int*)d_in[4];
    const int*   bias_index         = (const int*)d_in[5];
    const float* bias_value         = (const float*)d_in[6];
    float* out = (float*)d_out;

    unsigned char* W9Tf = (unsigned char*)d_ws;
    float* bias_dense = (float*)((char*)d_ws + W9T_BYTES);

    hipMemsetAsync(d_ws, 0, W9T_BYTES, stream);
    prep_weights<<<OC + 1, 256, 0, stream>>>(weight_value, image_weight_index,
                                             filter_lengths, start_points, W9Tf,
                                             bias_index, bias_value, bias_dense,
                                             in_sizes[5]);

    dim3 grid(HO / 2, NB);
    conv_mfma<<<grid, 256, 0, stream>>>(images, W9Tf, bias_dense, out);
}

// Round 23
// 57.975 us; speedup vs baseline: 1.1277x; 1.0359x over previous
//
#include <hip/hip_runtime.h>
#include <stdint.h>

#define IC 128
#define OC 256
#define RR 64
#define CCOLS 64
#define HO 62
#define WO 62
#define NB 16

// Fragment-major dense bf16 weights: W9Tf[chunk][g][lane][16B],
// chunk = kp*8+ck (72), g = oc>>5 (8), lane = (oc&31)+32*khalf.
#define W9T_BYTES (9 * OC * IC * 2)   // 589824
#define CHUNK_STRIDE 8192
// B LDS layout: [krow 4][octet 16][x 64][16B] = 64 KB + 64 B pad.
#define LDS_TOTAL 65600

typedef __bf16 bf16x8 __attribute__((ext_vector_type(8)));
typedef float f32x16 __attribute__((ext_vector_type(16)));

__device__ __forceinline__ unsigned short f2bf(float f) {
    unsigned u = __builtin_bit_cast(unsigned, f);
    u += 0x7FFFu + ((u >> 16) & 1u);   // round-to-nearest-even
    return (unsigned short)(u >> 16);
}

// prep: blocks 0..OC-1 scatter weights; block OC densifies the bias.
__global__ void prep_weights(const float* __restrict__ wv,
                             const int* __restrict__ iwi,
                             const int* __restrict__ flen,
                             const int* __restrict__ sp,
                             unsigned char* __restrict__ W9Tf,
                             const int* __restrict__ bias_index,
                             const float* __restrict__ bias_value,
                             float* __restrict__ bias_dense, int nbias) {
    if (blockIdx.x == OC) {
        int t = threadIdx.x;
        if (t < OC) bias_dense[t] = 0.f;
        __syncthreads();
        if (t < nbias) atomicAdd(&bias_dense[bias_index[t]], bias_value[t]);
        return;
    }
    const int oc = blockIdx.x;
    const int s = sp[oc];
    const int n = flen[oc];
    const int g = oc >> 5;
    for (int t = threadIdx.x; t < n; t += blockDim.x) {
        const int ix = iwi[s + t];          // c*4096 + ky*64 + kx
        const int c = ix >> 12;
        const int rem = ix & 4095;
        const int ky = rem >> 6, kx = rem & 63;
        const int kp = ky * 3 + kx;
        const int ck = c >> 4;
        const int khalf = (c >> 3) & 1;
        const int lane = (oc & 31) + (khalf << 5);
        const size_t off = (size_t)(kp * 8 + ck) * CHUNK_STRIDE +
                           g * 1024 + lane * 16 + (c & 7) * 2;
        *(unsigned short*)(W9Tf + off) = f2bf(wv[s + t]);
    }
}

// One K-chunk step, 8 chains. R23 vs R22: zero in-loop VALU — B offsets
// fold into ds_read offset: immediates (base VGPR bB), A addresses are a
// fixed 32-bit v_off + uniform SGPR-pair base (SALU only); no
// sched_barrier — ordering via tying ALL consumed regs into the waitcnt
// (rule #18 satisfied by true data deps); B reg rotation via even/odd
// macro sets (no swap movs).
#define KSTEP_CORE(IDX, AV0, AV1, C00, C01, C10, C11, N00, N01, N10, N11, VN, LGN) \
  {                                                                           \
    if constexpr ((IDX) + 1 < 72) {                                           \
      constexpr int i1_ = (IDX) + 1;                                          \
      constexpr int kp1_ = i1_ >> 3, ck1_ = i1_ & 7;                          \
      constexpr int o1_ = (kp1_ / 3) * 16384 + ck1_ * 2048 + (kp1_ % 3) * 16; \
      asm volatile("ds_read_b128 %0, %1 offset:%c2" : "=v"(N00) : "v"(bB), "i"(o1_)); \
      asm volatile("ds_read_b128 %0, %1 offset:%c2" : "=v"(N01) : "v"(bB), "i"(o1_ + 512)); \
      asm volatile("ds_read_b128 %0, %1 offset:%c2" : "=v"(N10) : "v"(bB), "i"(o1_ + 16384)); \
      asm volatile("ds_read_b128 %0, %1 offset:%c2" : "=v"(N11) : "v"(bB), "i"(o1_ + 16896)); \
    }                                                                         \
    asm volatile("s_waitcnt vmcnt(" VN ") lgkmcnt(" LGN ")"                   \
                 : "+v"(AV0), "+v"(AV1), "+v"(C00), "+v"(C01), "+v"(C10), "+v"(C11)); \
    __builtin_amdgcn_s_setprio(1);                                            \
    c000 = __builtin_amdgcn_mfma_f32_32x32x16_bf16(AV0, C00, c000, 0, 0, 0);  \
    c100 = __builtin_amdgcn_mfma_f32_32x32x16_bf16(AV1, C00, c100, 0, 0, 0);  \
    c001 = __builtin_amdgcn_mfma_f32_32x32x16_bf16(AV0, C01, c001, 0, 0, 0);  \
    c101 = __builtin_amdgcn_mfma_f32_32x32x16_bf16(AV1, C01, c101, 0, 0, 0);  \
    c010 = __builtin_amdgcn_mfma_f32_32x32x16_bf16(AV0, C10, c010, 0, 0, 0);  \
    c110 = __builtin_amdgcn_mfma_f32_32x32x16_bf16(AV1, C10, c110, 0, 0, 0);  \
    c011 = __builtin_amdgcn_mfma_f32_32x32x16_bf16(AV0, C11, c011, 0, 0, 0);  \
    c111 = __builtin_amdgcn_mfma_f32_32x32x16_bf16(AV1, C11, c111, 0, 0, 0);  \
    __builtin_amdgcn_s_setprio(0);                                            \
    if constexpr ((IDX) + 4 < 72) {                                           \
      asm volatile("global_load_dwordx4 %0, %1, %2" : "=v"(AV0)               \
                   : "v"(vA0), "s"((const void*)(pW + (size_t)((IDX) + 4) * CHUNK_STRIDE))); \
      asm volatile("global_load_dwordx4 %0, %1, %2" : "=v"(AV1)               \
                   : "v"(vA1), "s"((const void*)(pW + (size_t)((IDX) + 4) * CHUNK_STRIDE))); \
    }                                                                         \
  }

#define KE(IDX, AV0, AV1, VN, LGN) \
  KSTEP_CORE(IDX, AV0, AV1, bX00, bX01, bX10, bX11, bY00, bY01, bY10, bY11, VN, LGN)
#define KO(IDX, AV0, AV1, VN, LGN) \
  KSTEP_CORE(IDX, AV0, AV1, bY00, bY01, bY10, bY11, bX00, bX01, bX10, bX11, VN, LGN)

#define K4(I) KE((I)+0, a0S0, a1S0, "6", "4") KO((I)+1, a0S1, a1S1, "6", "4") \
              KE((I)+2, a0S2, a1S2, "6", "4") KO((I)+3, a0S3, a1S3, "6", "4")

// Block = (b, 2 output rows) x all 256 oc. 256 threads = 4 waves.
// Wave w: oc-groups {2w,2w+1} x 2 n-tiles x 2 y-rows = 8 chains, 8 MFMAs
// per step. R22 geometry (52us, MfmaUtil 28%); this round removes the
// ~350 cyc/step/SIMD of in-loop VALU addressing and the sched_barrier
// order-pinning (the wave serial-timeline is the wall at 2 waves/SIMD).
__global__ __launch_bounds__(256, 1) void conv_mfma(
    const float* __restrict__ images,
    const unsigned char* __restrict__ W9Tf,
    const float* __restrict__ bias_dense,
    float* __restrict__ out)
{
    const int y0 = blockIdx.x * 2;
    const int b = blockIdx.y;
    const int t = threadIdx.x;
    const int w = t >> 6;             // 0..3
    const int l = t & 63;
    const int lm = l & 31;            // m-row / n-col within frag
    const int lhi = l >> 5;           // k-half

    __shared__ unsigned char lds[LDS_TOTAL];

    const float* __restrict__ imgb = images + (size_t)b * (IC * RR * CCOLS);

    // ---- stage B: 4 rows -> [krow][octet][x][16B] (conflict-free) ----
    {
        const int xs = t & 63;
        const int og = t >> 6;              // 0..3, wave-uniform
        #pragma unroll
        for (int krow = 0; krow < 4; ++krow) {
            #pragma unroll
            for (int h = 0; h < 4; ++h) {
                const int o = og + 4 * h;           // octet 0..15
                const int c0 = o * 8;
                const float* __restrict__ p =
                    imgb + (size_t)c0 * (RR * CCOLS) + (y0 + krow) * CCOLS + xs;
                unsigned v0, v1, v2, v3;
                v0 = (unsigned)f2bf(p[0])              | ((unsigned)f2bf(p[RR * CCOLS])     << 16);
                v1 = (unsigned)f2bf(p[2 * RR * CCOLS]) | ((unsigned)f2bf(p[3 * RR * CCOLS]) << 16);
                v2 = (unsigned)f2bf(p[4 * RR * CCOLS]) | ((unsigned)f2bf(p[5 * RR * CCOLS]) << 16);
                v3 = (unsigned)f2bf(p[6 * RR * CCOLS]) | ((unsigned)f2bf(p[7 * RR * CCOLS]) << 16);
                *(uint4*)(lds + krow * 16384 + o * 1024 + xs * 16) =
                    make_uint4(v0, v1, v2, v3);
            }
        }
    }

    // uniform A chunk base (SGPR pair); fixed per-lane 32-bit v-offsets
    const unsigned char* __restrict__ pW = W9Tf;
    const int vA0 = (2 * w + 0) * 1024 + l * 16;
    const int vA1 = (2 * w + 1) * 1024 + l * 16;
    // B base VGPR (LDS byte address); all chunk offsets are immediates
    const unsigned bB = (unsigned)(uintptr_t)(lds + lhi * 1024 + lm * 16);

    __syncthreads();   // B staged; all counters drained

    // prologue: A chunks 0..3 (both streams, issue order = count order)
    // and B step 0 in flight (all opaque)
    bf16x8 a0S0, a0S1, a0S2, a0S3, a1S0, a1S1, a1S2, a1S3;
    bf16x8 bX00, bX01, bX10, bX11, bY00, bY01, bY10, bY11;
    asm volatile("global_load_dwordx4 %0, %1, %2" : "=v"(a0S0) : "v"(vA0), "s"((const void*)(pW)));
    asm volatile("global_load_dwordx4 %0, %1, %2" : "=v"(a1S0) : "v"(vA1), "s"((const void*)(pW)));
    asm volatile("global_load_dwordx4 %0, %1, %2" : "=v"(a0S1) : "v"(vA0), "s"((const void*)(pW + CHUNK_STRIDE)));
    asm volatile("global_load_dwordx4 %0, %1, %2" : "=v"(a1S1) : "v"(vA1), "s"((const void*)(pW + CHUNK_STRIDE)));
    asm volatile("global_load_dwordx4 %0, %1, %2" : "=v"(a0S2) : "v"(vA0), "s"((const void*)(pW + 2 * CHUNK_STRIDE)));
    asm volatile("global_load_dwordx4 %0, %1, %2" : "=v"(a1S2) : "v"(vA1), "s"((const void*)(pW + 2 * CHUNK_STRIDE)));
    asm volatile("global_load_dwordx4 %0, %1, %2" : "=v"(a0S3) : "v"(vA0), "s"((const void*)(pW + 3 * CHUNK_STRIDE)));
    asm volatile("global_load_dwordx4 %0, %1, %2" : "=v"(a1S3) : "v"(vA1), "s"((const void*)(pW + 3 * CHUNK_STRIDE)));
    asm volatile("ds_read_b128 %0, %1" : "=v"(bX00) : "v"(bB));
    asm volatile("ds_read_b128 %0, %1 offset:512" : "=v"(bX01) : "v"(bB));
    asm volatile("ds_read_b128 %0, %1 offset:16384" : "=v"(bX10) : "v"(bB));
    asm volatile("ds_read_b128 %0, %1 offset:16896" : "=v"(bX11) : "v"(bB));

    // named accumulators c<m><yy><n> (static indexing -> no scratch)
    f32x16 c000 = {}, c001 = {}, c010 = {}, c011 = {};
    f32x16 c100 = {}, c101 = {}, c110 = {}, c111 = {};

    // 72 straight-line K-steps; steady vmcnt(6)/lgkmcnt(4); counted tail
    K4(0) K4(4) K4(8) K4(12) K4(16) K4(20) K4(24) K4(28) K4(32)
    K4(36) K4(40) K4(44) K4(48) K4(52) K4(56) K4(60) K4(64)
    KE(68, a0S0, a1S0, "6", "4") KO(69, a0S1, a1S1, "4", "4")
    KE(70, a0S2, a1S2, "2", "4") KO(71, a0S3, a1S3, "0", "0")

    // ---- epilogue: bias + store ----
    // C/D 32x32: col = lane&31, row = (reg&3) + 8*(reg>>2) + 4*(lane>>5)
    #pragma unroll
    for (int m = 0; m < 2; ++m) {
        const int ocw = (2 * w + m) * 32;
        const f32x16 d00 = m ? c100 : c000;   // [y0][n0]
        const f32x16 d01 = m ? c101 : c001;   // [y0][n1]
        const f32x16 d10 = m ? c110 : c010;   // [y1][n0]
        const f32x16 d11 = m ? c111 : c011;   // [y1][n1]
        #pragma unroll
        for (int r = 0; r < 16; ++r) {
            const int oc = ocw + (r & 3) + 8 * (r >> 2) + 4 * lhi;
            const float bv = bias_dense[oc];
            const size_t ob0 = (((size_t)b * OC + oc) * HO + y0) * WO;
            out[ob0 + lm] = d00[r] + bv;             // x = lm < 62 always
            if (lm < 30)
                out[ob0 + 32 + lm] = d01[r] + bv;    // x = 32+lm, clip at 62
            const size_t ob1 = ob0 + WO;             // row y0+1
            out[ob1 + lm] = d10[r] + bv;
            if (lm < 30)
                out[ob1 + 32 + lm] = d11[r] + bv;
        }
    }
}

extern "C" void kernel_launch(void* const* d_in, const int* in_sizes, int n_in,
                              void* d_out, int out_size, void* d_ws, size_t ws_size,
                              hipStream_t stream) {
    const float* images             = (const float*)d_in[0];
    const float* weight_value       = (const float*)d_in[1];
    const int*   image_weight_index = (const int*)d_in[2];
    const int*   filter_lengths     = (const int*)d_in[3];
    const int*   start_points       = (const int*)d_in[4];
    const int*   bias_index         = (const int*)d_in[5];
    const float* bias_value         = (const float*)d_in[6];
    float* out = (float*)d_out;

    unsigned char* W9Tf = (unsigned char*)d_ws;
    float* bias_dense = (float*)((char*)d_ws + W9T_BYTES);

    hipMemsetAsync(d_ws, 0, W9T_BYTES, stream);
    prep_weights<<<OC + 1, 256, 0, stream>>>(weight_value, image_weight_index,
                                             filter_lengths, start_points, W9Tf,
                                             bias_index, bias_value, bias_dense,
                                             in_sizes[5]);

    dim3 grid(HO / 2, NB);
    conv_mfma<<<grid, 256, 0, stream>>>(images, W9Tf, bias_dense, out);
}

// Round 24
// 57.760 us; speedup vs baseline: 1.1319x; 1.0037x over previous
//
#include <hip/hip_runtime.h>
#include <stdint.h>

#define IC 128
#define OC 256
#define RR 64
#define CCOLS 64
#define HO 62
#define WO 62
#define NB 16

// Fragment-major dense bf16 weights: W9Tf[chunk][g][lane][16B],
// chunk = kp*8+ck (72), g = oc>>5 (8), lane = (oc&31)+32*khalf.
#define W9T_BYTES (9 * OC * IC * 2)   // 589824
#define CHUNK_STRIDE 8192
// B LDS layout: [krow 4][octet 16][x 64][16B] = EXACTLY 65536 B.
// R23 used 65600 (64B overrun pad) -> LDS_Block_Size 66048 and only ONE
// block resident/CU (occupancy 15%). The overrun reads (n=1 tile, lanes
// lm>=30, x=62..65, outputs never stored) are instead redirected via a
// clamped base reg bB1 (lm capped at 29 -> max byte 65520 < 65536).
#define LDS_TOTAL 65536

typedef __bf16 bf16x8 __attribute__((ext_vector_type(8)));
typedef float f32x16 __attribute__((ext_vector_type(16)));

__device__ __forceinline__ unsigned short f2bf(float f) {
    unsigned u = __builtin_bit_cast(unsigned, f);
    u += 0x7FFFu + ((u >> 16) & 1u);   // round-to-nearest-even
    return (unsigned short)(u >> 16);
}

// prep: blocks 0..OC-1 scatter weights; block OC densifies the bias.
__global__ void prep_weights(const float* __restrict__ wv,
                             const int* __restrict__ iwi,
                             const int* __restrict__ flen,
                             const int* __restrict__ sp,
                             unsigned char* __restrict__ W9Tf,
                             const int* __restrict__ bias_index,
                             const float* __restrict__ bias_value,
                             float* __restrict__ bias_dense, int nbias) {
    if (blockIdx.x == OC) {
        int t = threadIdx.x;
        if (t < OC) bias_dense[t] = 0.f;
        __syncthreads();
        if (t < nbias) atomicAdd(&bias_dense[bias_index[t]], bias_value[t]);
        return;
    }
    const int oc = blockIdx.x;
    const int s = sp[oc];
    const int n = flen[oc];
    const int g = oc >> 5;
    for (int t = threadIdx.x; t < n; t += blockDim.x) {
        const int ix = iwi[s + t];          // c*4096 + ky*64 + kx
        const int c = ix >> 12;
        const int rem = ix & 4095;
        const int ky = rem >> 6, kx = rem & 63;
        const int kp = ky * 3 + kx;
        const int ck = c >> 4;
        const int khalf = (c >> 3) & 1;
        const int lane = (oc & 31) + (khalf << 5);
        const size_t off = (size_t)(kp * 8 + ck) * CHUNK_STRIDE +
                           g * 1024 + lane * 16 + (c & 7) * 2;
        *(unsigned short*)(W9Tf + off) = f2bf(wv[s + t]);
    }
}

// One K-chunk step, 8 chains. n=0 reads off bB0 (true lm), n=1 reads off
// bB1 (lm clamped to 29; lanes 30,31 duplicate x=61 -> outputs discarded).
#define KSTEP_CORE(IDX, AV0, AV1, C00, C01, C10, C11, N00, N01, N10, N11, VN, LGN) \
  {                                                                           \
    if constexpr ((IDX) + 1 < 72) {                                           \
      constexpr int i1_ = (IDX) + 1;                                          \
      constexpr int kp1_ = i1_ >> 3, ck1_ = i1_ & 7;                          \
      constexpr int o1_ = (kp1_ / 3) * 16384 + ck1_ * 2048 + (kp1_ % 3) * 16; \
      asm volatile("ds_read_b128 %0, %1 offset:%c2" : "=v"(N00) : "v"(bB0), "i"(o1_)); \
      asm volatile("ds_read_b128 %0, %1 offset:%c2" : "=v"(N01) : "v"(bB1), "i"(o1_ + 512)); \
      asm volatile("ds_read_b128 %0, %1 offset:%c2" : "=v"(N10) : "v"(bB0), "i"(o1_ + 16384)); \
      asm volatile("ds_read_b128 %0, %1 offset:%c2" : "=v"(N11) : "v"(bB1), "i"(o1_ + 16896)); \
    }                                                                         \
    asm volatile("s_waitcnt vmcnt(" VN ") lgkmcnt(" LGN ")"                   \
                 : "+v"(AV0), "+v"(AV1), "+v"(C00), "+v"(C01), "+v"(C10), "+v"(C11)); \
    __builtin_amdgcn_s_setprio(1);                                            \
    c000 = __builtin_amdgcn_mfma_f32_32x32x16_bf16(AV0, C00, c000, 0, 0, 0);  \
    c100 = __builtin_amdgcn_mfma_f32_32x32x16_bf16(AV1, C00, c100, 0, 0, 0);  \
    c001 = __builtin_amdgcn_mfma_f32_32x32x16_bf16(AV0, C01, c001, 0, 0, 0);  \
    c101 = __builtin_amdgcn_mfma_f32_32x32x16_bf16(AV1, C01, c101, 0, 0, 0);  \
    c010 = __builtin_amdgcn_mfma_f32_32x32x16_bf16(AV0, C10, c010, 0, 0, 0);  \
    c110 = __builtin_amdgcn_mfma_f32_32x32x16_bf16(AV1, C10, c110, 0, 0, 0);  \
    c011 = __builtin_amdgcn_mfma_f32_32x32x16_bf16(AV0, C11, c011, 0, 0, 0);  \
    c111 = __builtin_amdgcn_mfma_f32_32x32x16_bf16(AV1, C11, c111, 0, 0, 0);  \
    __builtin_amdgcn_s_setprio(0);                                            \
    if constexpr ((IDX) + 4 < 72) {                                           \
      asm volatile("global_load_dwordx4 %0, %1, %2" : "=v"(AV0)               \
                   : "v"(vA0), "s"((const void*)(pW + (size_t)((IDX) + 4) * CHUNK_STRIDE))); \
      asm volatile("global_load_dwordx4 %0, %1, %2" : "=v"(AV1)               \
                   : "v"(vA1), "s"((const void*)(pW + (size_t)((IDX) + 4) * CHUNK_STRIDE))); \
    }                                                                         \
  }

#define KE(IDX, AV0, AV1, VN, LGN) \
  KSTEP_CORE(IDX, AV0, AV1, bX00, bX01, bX10, bX11, bY00, bY01, bY10, bY11, VN, LGN)
#define KO(IDX, AV0, AV1, VN, LGN) \
  KSTEP_CORE(IDX, AV0, AV1, bY00, bY01, bY10, bY11, bX00, bX01, bX10, bX11, VN, LGN)

#define K4(I) KE((I)+0, a0S0, a1S0, "6", "4") KO((I)+1, a0S1, a1S1, "6", "4") \
              KE((I)+2, a0S2, a1S2, "6", "4") KO((I)+3, a0S3, a1S3, "6", "4")

// Block = (b, 2 output rows) x all 256 oc. 256 threads = 4 waves.
// Wave w: oc-groups {2w,2w+1} x 2 n-tiles x 2 y-rows = 8 chains, 8 MFMAs
// per step. R23 structure with LDS trimmed to exactly 64 KiB so TWO
// blocks co-reside per CU (2 waves/SIMD; R23's 65600 B allocation left
// occupancy at 15% = 1 block/CU, capping MfmaUtil at 28%).
__global__ __launch_bounds__(256, 1) void conv_mfma(
    const float* __restrict__ images,
    const unsigned char* __restrict__ W9Tf,
    const float* __restrict__ bias_dense,
    float* __restrict__ out)
{
    const int y0 = blockIdx.x * 2;
    const int b = blockIdx.y;
    const int t = threadIdx.x;
    const int w = t >> 6;             // 0..3
    const int l = t & 63;
    const int lm = l & 31;            // m-row / n-col within frag
    const int lhi = l >> 5;           // k-half

    __shared__ unsigned char lds[LDS_TOTAL];

    const float* __restrict__ imgb = images + (size_t)b * (IC * RR * CCOLS);

    // ---- stage B: 4 rows -> [krow][octet][x][16B] (conflict-free) ----
    {
        const int xs = t & 63;
        const int og = t >> 6;              // 0..3, wave-uniform
        #pragma unroll
        for (int krow = 0; krow < 4; ++krow) {
            #pragma unroll
            for (int h = 0; h < 4; ++h) {
                const int o = og + 4 * h;           // octet 0..15
                const int c0 = o * 8;
                const float* __restrict__ p =
                    imgb + (size_t)c0 * (RR * CCOLS) + (y0 + krow) * CCOLS + xs;
                unsigned v0, v1, v2, v3;
                v0 = (unsigned)f2bf(p[0])              | ((unsigned)f2bf(p[RR * CCOLS])     << 16);
                v1 = (unsigned)f2bf(p[2 * RR * CCOLS]) | ((unsigned)f2bf(p[3 * RR * CCOLS]) << 16);
                v2 = (unsigned)f2bf(p[4 * RR * CCOLS]) | ((unsigned)f2bf(p[5 * RR * CCOLS]) << 16);
                v3 = (unsigned)f2bf(p[6 * RR * CCOLS]) | ((unsigned)f2bf(p[7 * RR * CCOLS]) << 16);
                *(uint4*)(lds + krow * 16384 + o * 1024 + xs * 16) =
                    make_uint4(v0, v1, v2, v3);
            }
        }
    }

    // uniform A chunk base (SGPR pair); fixed per-lane 32-bit v-offsets
    const unsigned char* __restrict__ pW = W9Tf;
    const int vA0 = (2 * w + 0) * 1024 + l * 16;
    const int vA1 = (2 * w + 1) * 1024 + l * 16;
    // B base VGPRs: bB0 true lm; bB1 clamps lm to 29 (keeps all n=1 reads
    // below 64 KiB; clamped lanes' outputs are never stored)
    const int lmc = lm > 29 ? 29 : lm;
    const unsigned bB0 = (unsigned)(uintptr_t)(lds + lhi * 1024 + lm * 16);
    const unsigned bB1 = (unsigned)(uintptr_t)(lds + lhi * 1024 + lmc * 16);

    __syncthreads();   // B staged; all counters drained

    // prologue: A chunks 0..3 (both streams) and B step 0 in flight
    bf16x8 a0S0, a0S1, a0S2, a0S3, a1S0, a1S1, a1S2, a1S3;
    bf16x8 bX00, bX01, bX10, bX11, bY00, bY01, bY10, bY11;
    asm volatile("global_load_dwordx4 %0, %1, %2" : "=v"(a0S0) : "v"(vA0), "s"((const void*)(pW)));
    asm volatile("global_load_dwordx4 %0, %1, %2" : "=v"(a1S0) : "v"(vA1), "s"((const void*)(pW)));
    asm volatile("global_load_dwordx4 %0, %1, %2" : "=v"(a0S1) : "v"(vA0), "s"((const void*)(pW + CHUNK_STRIDE)));
    asm volatile("global_load_dwordx4 %0, %1, %2" : "=v"(a1S1) : "v"(vA1), "s"((const void*)(pW + CHUNK_STRIDE)));
    asm volatile("global_load_dwordx4 %0, %1, %2" : "=v"(a0S2) : "v"(vA0), "s"((const void*)(pW + 2 * CHUNK_STRIDE)));
    asm volatile("global_load_dwordx4 %0, %1, %2" : "=v"(a1S2) : "v"(vA1), "s"((const void*)(pW + 2 * CHUNK_STRIDE)));
    asm volatile("global_load_dwordx4 %0, %1, %2" : "=v"(a0S3) : "v"(vA0), "s"((const void*)(pW + 3 * CHUNK_STRIDE)));
    asm volatile("global_load_dwordx4 %0, %1, %2" : "=v"(a1S3) : "v"(vA1), "s"((const void*)(pW + 3 * CHUNK_STRIDE)));
    asm volatile("ds_read_b128 %0, %1" : "=v"(bX00) : "v"(bB0));
    asm volatile("ds_read_b128 %0, %1 offset:512" : "=v"(bX01) : "v"(bB1));
    asm volatile("ds_read_b128 %0, %1 offset:16384" : "=v"(bX10) : "v"(bB0));
    asm volatile("ds_read_b128 %0, %1 offset:16896" : "=v"(bX11) : "v"(bB1));

    // named accumulators c<m><yy><n> (static indexing -> no scratch)
    f32x16 c000 = {}, c001 = {}, c010 = {}, c011 = {};
    f32x16 c100 = {}, c101 = {}, c110 = {}, c111 = {};

    // 72 straight-line K-steps; steady vmcnt(6)/lgkmcnt(4); counted tail
    K4(0) K4(4) K4(8) K4(12) K4(16) K4(20) K4(24) K4(28) K4(32)
    K4(36) K4(40) K4(44) K4(48) K4(52) K4(56) K4(60) K4(64)
    KE(68, a0S0, a1S0, "6", "4") KO(69, a0S1, a1S1, "4", "4")
    KE(70, a0S2, a1S2, "2", "4") KO(71, a0S3, a1S3, "0", "0")

    // ---- epilogue: bias + store ----
    // C/D 32x32: col = lane&31, row = (reg&3) + 8*(reg>>2) + 4*(lane>>5)
    #pragma unroll
    for (int m = 0; m < 2; ++m) {
        const int ocw = (2 * w + m) * 32;
        const f32x16 d00 = m ? c100 : c000;   // [y0][n0]
        const f32x16 d01 = m ? c101 : c001;   // [y0][n1]
        const f32x16 d10 = m ? c110 : c010;   // [y1][n0]
        const f32x16 d11 = m ? c111 : c011;   // [y1][n1]
        #pragma unroll
        for (int r = 0; r < 16; ++r) {
            const int oc = ocw + (r & 3) + 8 * (r >> 2) + 4 * lhi;
            const float bv = bias_dense[oc];
            const size_t ob0 = (((size_t)b * OC + oc) * HO + y0) * WO;
            out[ob0 + lm] = d00[r] + bv;             // x = lm < 62 always
            if (lm < 30)
                out[ob0 + 32 + lm] = d01[r] + bv;    // x = 32+lm, clip at 62
            const size_t ob1 = ob0 + WO;             // row y0+1
            out[ob1 + lm] = d10[r] + bv;
            if (lm < 30)
                out[ob1 + 32 + lm] = d11[r] + bv;
        }
    }
}

extern "C" void kernel_launch(void* const* d_in, const int* in_sizes, int n_in,
                              void* d_out, int out_size, void* d_ws, size_t ws_size,
                              hipStream_t stream) {
    const float* images             = (const float*)d_in[0];
    const float* weight_value       = (const float*)d_in[1];
    const int*   image_weight_index = (const int*)d_in[2];
    const int*   filter_lengths     = (const int*)d_in[3];
    const int*   start_points       = (const int*)d_in[4];
    const int*   bias_index         = (const int*)d_in[5];
    const float* bias_value         = (const float*)d_in[6];
    float* out = (float*)d_out;

    unsigned char* W9Tf = (unsigned char*)d_ws;
    float* bias_dense = (float*)((char*)d_ws + W9T_BYTES);

    hipMemsetAsync(d_ws, 0, W9T_BYTES, stream);
    prep_weights<<<OC + 1, 256, 0, stream>>>(weight_value, image_weight_index,
                                             filter_lengths, start_points, W9Tf,
                                             bias_index, bias_value, bias_dense,
                                             in_sizes[5]);

    dim3 grid(HO / 2, NB);
    conv_mfma<<<grid, 256, 0, stream>>>(images, W9Tf, bias_dense, out);
}

// Round 25
// 56.368 us; speedup vs baseline: 1.1599x; 1.0247x over previous
//
#include <hip/hip_runtime.h>
#include <stdint.h>

#define IC 128
#define OC 256
#define RR 64
#define CCOLS 64
#define HO 62
#define WO 62
#define NB 16

// Fragment-major dense bf16 weights: W9Tf[chunk][g][lane][16B],
// chunk = kp*8+ck (72), g = oc>>5 (8), lane = (oc&31)+32*khalf.
#define W9T_BYTES (9 * OC * IC * 2)   // 589824
#define CHUNK_STRIDE 8192
// B LDS layout: [krow 6][octet 16][x 64][16B] = 98304 B (6 image rows
// cover 4 output rows). Max read = 98288 (bB1 lm-clamp) < 98304.
#define LDS_TOTAL 98304

typedef __bf16 bf16x8 __attribute__((ext_vector_type(8)));
typedef float f32x16 __attribute__((ext_vector_type(16)));

__device__ __forceinline__ unsigned short f2bf(float f) {
    unsigned u = __builtin_bit_cast(unsigned, f);
    u += 0x7FFFu + ((u >> 16) & 1u);   // round-to-nearest-even
    return (unsigned short)(u >> 16);
}

// prep: blocks 0..OC-1 scatter weights; block OC densifies the bias.
__global__ void prep_weights(const float* __restrict__ wv,
                             const int* __restrict__ iwi,
                             const int* __restrict__ flen,
                             const int* __restrict__ sp,
                             unsigned char* __restrict__ W9Tf,
                             const int* __restrict__ bias_index,
                             const float* __restrict__ bias_value,
                             float* __restrict__ bias_dense, int nbias) {
    if (blockIdx.x == OC) {
        int t = threadIdx.x;
        if (t < OC) bias_dense[t] = 0.f;
        __syncthreads();
        if (t < nbias) atomicAdd(&bias_dense[bias_index[t]], bias_value[t]);
        return;
    }
    const int oc = blockIdx.x;
    const int s = sp[oc];
    const int n = flen[oc];
    const int g = oc >> 5;
    for (int t = threadIdx.x; t < n; t += blockDim.x) {
        const int ix = iwi[s + t];          // c*4096 + ky*64 + kx
        const int c = ix >> 12;
        const int rem = ix & 4095;
        const int ky = rem >> 6, kx = rem & 63;
        const int kp = ky * 3 + kx;
        const int ck = c >> 4;
        const int khalf = (c >> 3) & 1;
        const int lane = (oc & 31) + (khalf << 5);
        const size_t off = (size_t)(kp * 8 + ck) * CHUNK_STRIDE +
                           g * 1024 + lane * 16 + (c & 7) * 2;
        *(unsigned short*)(W9Tf + off) = f2bf(wv[s + t]);
    }
}

// One K-chunk step, 8 chains (2 oc x 2 y x 2 n). Identical to R24's step;
// bB0/bB1 now carry the wave's y-pair base (+32768*(w>>2)). Offset
// immediates max 64032 < 65536 (16-bit ds offset) OK.
#define KSTEP_CORE(IDX, AV0, AV1, C00, C01, C10, C11, N00, N01, N10, N11, VN, LGN) \
  {                                                                           \
    if constexpr ((IDX) + 1 < 72) {                                           \
      constexpr int i1_ = (IDX) + 1;                                          \
      constexpr int kp1_ = i1_ >> 3, ck1_ = i1_ & 7;                          \
      constexpr int o1_ = (kp1_ / 3) * 16384 + ck1_ * 2048 + (kp1_ % 3) * 16; \
      asm volatile("ds_read_b128 %0, %1 offset:%c2" : "=v"(N00) : "v"(bB0), "i"(o1_)); \
      asm volatile("ds_read_b128 %0, %1 offset:%c2" : "=v"(N01) : "v"(bB1), "i"(o1_ + 512)); \
      asm volatile("ds_read_b128 %0, %1 offset:%c2" : "=v"(N10) : "v"(bB0), "i"(o1_ + 16384)); \
      asm volatile("ds_read_b128 %0, %1 offset:%c2" : "=v"(N11) : "v"(bB1), "i"(o1_ + 16896)); \
    }                                                                         \
    asm volatile("s_waitcnt vmcnt(" VN ") lgkmcnt(" LGN ")"                   \
                 : "+v"(AV0), "+v"(AV1), "+v"(C00), "+v"(C01), "+v"(C10), "+v"(C11)); \
    __builtin_amdgcn_s_setprio(1);                                            \
    c000 = __builtin_amdgcn_mfma_f32_32x32x16_bf16(AV0, C00, c000, 0, 0, 0);  \
    c100 = __builtin_amdgcn_mfma_f32_32x32x16_bf16(AV1, C00, c100, 0, 0, 0);  \
    c001 = __builtin_amdgcn_mfma_f32_32x32x16_bf16(AV0, C01, c001, 0, 0, 0);  \
    c101 = __builtin_amdgcn_mfma_f32_32x32x16_bf16(AV1, C01, c101, 0, 0, 0);  \
    c010 = __builtin_amdgcn_mfma_f32_32x32x16_bf16(AV0, C10, c010, 0, 0, 0);  \
    c110 = __builtin_amdgcn_mfma_f32_32x32x16_bf16(AV1, C10, c110, 0, 0, 0);  \
    c011 = __builtin_amdgcn_mfma_f32_32x32x16_bf16(AV0, C11, c011, 0, 0, 0);  \
    c111 = __builtin_amdgcn_mfma_f32_32x32x16_bf16(AV1, C11, c111, 0, 0, 0);  \
    __builtin_amdgcn_s_setprio(0);                                            \
    if constexpr ((IDX) + 4 < 72) {                                           \
      asm volatile("global_load_dwordx4 %0, %1, %2" : "=v"(AV0)               \
                   : "v"(vA0), "s"((const void*)(pW + (size_t)((IDX) + 4) * CHUNK_STRIDE))); \
      asm volatile("global_load_dwordx4 %0, %1, %2" : "=v"(AV1)               \
                   : "v"(vA1), "s"((const void*)(pW + (size_t)((IDX) + 4) * CHUNK_STRIDE))); \
    }                                                                         \
  }

#define KE(IDX, AV0, AV1, VN, LGN) \
  KSTEP_CORE(IDX, AV0, AV1, bX00, bX01, bX10, bX11, bY00, bY01, bY10, bY11, VN, LGN)
#define KO(IDX, AV0, AV1, VN, LGN) \
  KSTEP_CORE(IDX, AV0, AV1, bY00, bY01, bY10, bY11, bX00, bX01, bX10, bX11, VN, LGN)

#define K4(I) KE((I)+0, a0S0, a1S0, "6", "4") KO((I)+1, a0S1, a1S1, "6", "4") \
              KE((I)+2, a0S2, a1S2, "6", "4") KO((I)+3, a0S3, a1S3, "6", "4")

// Block = (b, 4 output rows) x all 256 oc. 512 threads = 8 waves.
// Waves 0-3: y-pair 0 (rows y0,y0+1); waves 4-7: y-pair 1 (y0+2,y0+3).
// Each wave: oc-groups {2(w&3), 2(w&3)+1} x 2 n x 2 y = 8 chains/step.
// 8-wave block -> 2 waves/SIMD GUARANTEED co-resident (R22-24's 2-block
// co-scheduling never materialized; occupancy stuck at 1 block/CU).
// Grid = 16 x 16 = 256 blocks = exactly 1/CU: no multi-round imbalance.
// Arch VGPR ~116 <= 128 cap of the 2-wave tier; acc 128 AGPR; no spill.
__global__ __launch_bounds__(512, 2) void conv_mfma(
    const float* __restrict__ images,
    const unsigned char* __restrict__ W9Tf,
    const float* __restrict__ bias_dense,
    float* __restrict__ out)
{
    int y0 = blockIdx.x * 4;
    if (y0 > 58) y0 = 58;             // tile 15: dup rows 58-61 (identical)
    const int b = blockIdx.y;
    const int t = threadIdx.x;
    const int w = t >> 6;             // 0..7
    const int wq = w & 3;             // oc-pair index
    const int ypg = w >> 2;           // y-pair index 0/1
    const int l = t & 63;
    const int lm = l & 31;            // m-row / n-col within frag
    const int lhi = l >> 5;           // k-half

    __shared__ unsigned char lds[LDS_TOTAL];

    const float* __restrict__ imgb = images + (size_t)b * (IC * RR * CCOLS);

    // ---- stage B: 6 rows -> [krow][octet][x][16B] (conflict-free) ----
    {
        const int xs = t & 63;
        const int og = t >> 6;              // 0..7, wave-uniform
        #pragma unroll
        for (int krow = 0; krow < 6; ++krow) {
            #pragma unroll
            for (int h = 0; h < 2; ++h) {
                const int o = og + 8 * h;           // octet 0..15
                const int c0 = o * 8;
                const float* __restrict__ p =
                    imgb + (size_t)c0 * (RR * CCOLS) + (y0 + krow) * CCOLS + xs;
                unsigned v0, v1, v2, v3;
                v0 = (unsigned)f2bf(p[0])              | ((unsigned)f2bf(p[RR * CCOLS])     << 16);
                v1 = (unsigned)f2bf(p[2 * RR * CCOLS]) | ((unsigned)f2bf(p[3 * RR * CCOLS]) << 16);
                v2 = (unsigned)f2bf(p[4 * RR * CCOLS]) | ((unsigned)f2bf(p[5 * RR * CCOLS]) << 16);
                v3 = (unsigned)f2bf(p[6 * RR * CCOLS]) | ((unsigned)f2bf(p[7 * RR * CCOLS]) << 16);
                *(uint4*)(lds + krow * 16384 + o * 1024 + xs * 16) =
                    make_uint4(v0, v1, v2, v3);
            }
        }
    }

    // uniform A chunk base (SGPR pair); fixed per-lane 32-bit v-offsets
    const unsigned char* __restrict__ pW = W9Tf;
    const int vA0 = (2 * wq + 0) * 1024 + l * 16;
    const int vA1 = (2 * wq + 1) * 1024 + l * 16;
    // B base VGPRs (include the wave's y-pair base). bB1 clamps lm to 29
    // (keeps all n=1 reads in-bounds; clamped lanes' outputs never stored).
    const int lmc = lm > 29 ? 29 : lm;
    const unsigned bB0 = (unsigned)(uintptr_t)(lds + ypg * 32768 + lhi * 1024 + lm * 16);
    const unsigned bB1 = (unsigned)(uintptr_t)(lds + ypg * 32768 + lhi * 1024 + lmc * 16);

    __syncthreads();   // B staged; all counters drained

    // prologue: A chunks 0..3 (both streams) and B step 0 in flight
    bf16x8 a0S0, a0S1, a0S2, a0S3, a1S0, a1S1, a1S2, a1S3;
    bf16x8 bX00, bX01, bX10, bX11, bY00, bY01, bY10, bY11;
    asm volatile("global_load_dwordx4 %0, %1, %2" : "=v"(a0S0) : "v"(vA0), "s"((const void*)(pW)));
    asm volatile("global_load_dwordx4 %0, %1, %2" : "=v"(a1S0) : "v"(vA1), "s"((const void*)(pW)));
    asm volatile("global_load_dwordx4 %0, %1, %2" : "=v"(a0S1) : "v"(vA0), "s"((const void*)(pW + CHUNK_STRIDE)));
    asm volatile("global_load_dwordx4 %0, %1, %2" : "=v"(a1S1) : "v"(vA1), "s"((const void*)(pW + CHUNK_STRIDE)));
    asm volatile("global_load_dwordx4 %0, %1, %2" : "=v"(a0S2) : "v"(vA0), "s"((const void*)(pW + 2 * CHUNK_STRIDE)));
    asm volatile("global_load_dwordx4 %0, %1, %2" : "=v"(a1S2) : "v"(vA1), "s"((const void*)(pW + 2 * CHUNK_STRIDE)));
    asm volatile("global_load_dwordx4 %0, %1, %2" : "=v"(a0S3) : "v"(vA0), "s"((const void*)(pW + 3 * CHUNK_STRIDE)));
    asm volatile("global_load_dwordx4 %0, %1, %2" : "=v"(a1S3) : "v"(vA1), "s"((const void*)(pW + 3 * CHUNK_STRIDE)));
    asm volatile("ds_read_b128 %0, %1" : "=v"(bX00) : "v"(bB0));
    asm volatile("ds_read_b128 %0, %1 offset:512" : "=v"(bX01) : "v"(bB1));
    asm volatile("ds_read_b128 %0, %1 offset:16384" : "=v"(bX10) : "v"(bB0));
    asm volatile("ds_read_b128 %0, %1 offset:16896" : "=v"(bX11) : "v"(bB1));

    // named accumulators c<m><yy><n> (static indexing -> no scratch)
    f32x16 c000 = {}, c001 = {}, c010 = {}, c011 = {};
    f32x16 c100 = {}, c101 = {}, c110 = {}, c111 = {};

    // 72 straight-line K-steps; steady vmcnt(6)/lgkmcnt(4); counted tail
    K4(0) K4(4) K4(8) K4(12) K4(16) K4(20) K4(24) K4(28) K4(32)
    K4(36) K4(40) K4(44) K4(48) K4(52) K4(56) K4(60) K4(64)
    KE(68, a0S0, a1S0, "6", "4") KO(69, a0S1, a1S1, "4", "4")
    KE(70, a0S2, a1S2, "2", "4") KO(71, a0S3, a1S3, "0", "0")

    // ---- epilogue: bias + store ----
    // C/D 32x32: col = lane&31, row = (reg&3) + 8*(reg>>2) + 4*(lane>>5)
    const int yb = y0 + 2 * ypg;
    #pragma unroll
    for (int m = 0; m < 2; ++m) {
        const int ocw = (2 * wq + m) * 32;
        const f32x16 d00 = m ? c100 : c000;   // [yb][n0]
        const f32x16 d01 = m ? c101 : c001;   // [yb][n1]
        const f32x16 d10 = m ? c110 : c010;   // [yb+1][n0]
        const f32x16 d11 = m ? c111 : c011;   // [yb+1][n1]
        #pragma unroll
        for (int r = 0; r < 16; ++r) {
            const int oc = ocw + (r & 3) + 8 * (r >> 2) + 4 * lhi;
            const float bv = bias_dense[oc];
            const size_t ob0 = (((size_t)b * OC + oc) * HO + yb) * WO;
            out[ob0 + lm] = d00[r] + bv;             // x = lm < 62 always
            if (lm < 30)
                out[ob0 + 32 + lm] = d01[r] + bv;    // x = 32+lm, clip at 62
            const size_t ob1 = ob0 + WO;             // row yb+1
            out[ob1 + lm] = d10[r] + bv;
            if (lm < 30)
                out[ob1 + 32 + lm] = d11[r] + bv;
        }
    }
}

extern "C" void kernel_launch(void* const* d_in, const int* in_sizes, int n_in,
                              void* d_out, int out_size, void* d_ws, size_t ws_size,
                              hipStream_t stream) {
    const float* images             = (const float*)d_in[0];
    const float* weight_value       = (const float*)d_in[1];
    const int*   image_weight_index = (const int*)d_in[2];
    const int*   filter_lengths     = (const int*)d_in[3];
    const int*   start_points       = (const int*)d_in[4];
    const int*   bias_index         = (const int*)d_in[5];
    const float* bias_value         = (const float*)d_in[6];
    float* out = (float*)d_out;

    unsigned char* W9Tf = (unsigned char*)d_ws;
    float* bias_dense = (float*)((char*)d_ws + W9T_BYTES);

    hipMemsetAsync(d_ws, 0, W9T_BYTES, stream);
    prep_weights<<<OC + 1, 256, 0, stream>>>(weight_value, image_weight_index,
                                             filter_lengths, start_points, W9Tf,
                                             bias_index, bias_value, bias_dense,
                                             in_sizes[5]);

    dim3 grid(16, NB);
    conv_mfma<<<grid, 512, 0, stream>>>(images, W9Tf, bias_dense, out);
}